// Round 6
// baseline (1172.798 us; speedup 1.0000x reference)
//
#include <hip/hip_runtime.h>
#include <hip/hip_fp16.h>

typedef __attribute__((ext_vector_type(8))) _Float16 half8;
typedef __attribute__((ext_vector_type(4))) _Float16 half4;
typedef __attribute__((ext_vector_type(4))) float f32x4;

#define B_TOT 8192
#define HDIM  128
#define NDEEP 5
#define PDIM  196
#define QDIM  49
#define BM    16
#define NPHASE (QDIM + NDEEP)   // 54, even

__device__ __forceinline__ float tanh_fast(float v) {
    // tanh(v) = 1 - 2/(exp(2v)+1); exp(2v) = exp2(v * 2*log2(e)). Saturates at +-inf.
    float e = __builtin_amdgcn_exp2f(v * 2.885390082f);
    float r = __builtin_amdgcn_rcpf(e + 1.0f);
    return fmaf(-2.0f, r, 1.0f);
}

__device__ __forceinline__ float fquant(float v, float mn, float sc) {
    // 8-bit uniform fake-quant: IEEE f32 div + rint (half-even) to match numpy
    return rintf((v - mn) / sc) * sc + mn;
}

// Fully fused DFR. grid=512 x 512 thr (8 waves); LDS 44 KB -> TWO blocks/CU
// (16 waves/CU, 4/SIMD) with independent barriers for cross-block overlap.
// Block owns 16 batch rows. Wave w owns out-neuron cols [w*16, w*16+16) -> one
// 16x16 D-tile/layer. Weights bw[5][4] half8 = 80 VGPR; st[5] = 20 VGPR; fits
// the 128-reg cap of __launch_bounds__(512,4) without loop spills.
// Diagonal pipeline: phase p runs h0(t=p) and deep layer i at t=p-1-i; one
// barrier per phase (54 total).
__global__ __launch_bounds__(512, 4) void dfr_all(
    const float* __restrict__ x,    const float* __restrict__ cell_out,
    const float* __restrict__ W0,   const float* __restrict__ a0p,
    const float* __restrict__ Wd,   const float* __restrict__ adp,
    const float* __restrict__ p1W,  const float* __restrict__ p1b,
    const float* __restrict__ fc1W, const float* __restrict__ fc2W,
    const float* __restrict__ fc2b, float* __restrict__ out)
{
    __shared__ __align__(16) char smem[4096 + 10 * 4096];   // 44 KB
    float* pix  = (float*)smem;          // [16 batch][64] f32 (q cols 0..48 valid)
    char*  actp = smem + 4096;           // act[producer 0..4][slot 0..1]: 16 rows x 256 B, swizzled

    const int tid  = threadIdx.x;
    const int lane = tid & 63;
    const int w    = tid >> 6;           // wave 0..7 (owns out-neuron cols w*16..w*16+15)
    const int l15  = lane & 15;
    const int l4   = lane >> 4;
    const int r0   = blockIdx.x * BM;

    float* sred = (float*)smem;          // reduce scratch (dead before pix written)

    // ---- per-tensor min/max (block-redundant, L2-resident) ----
    float qmn[8], qsc[8];                // 0:p1W 1:W0 2:fc1W 3..7:Wd[0..4]
    {
        const float* srcs[8] = { p1W, W0, fc1W, Wd, Wd + HDIM*HDIM, Wd + 2*HDIM*HDIM,
                                 Wd + 3*HDIM*HDIM, Wd + 4*HDIM*HDIM };
        const int    ns[8]   = { QDIM*PDIM, HDIM, 8*HDIM, HDIM*HDIM, HDIM*HDIM,
                                 HDIM*HDIM, HDIM*HDIM, HDIM*HDIM };
#pragma unroll
        for (int s = 0; s < 8; s++) {
            const float* p = srcs[s]; const int n = ns[s];
            float mn = 1e30f, mx = -1e30f;
            for (int i = tid; i < n; i += 512) { float v = p[i]; mn = fminf(mn, v); mx = fmaxf(mx, v); }
            for (int off = 32; off; off >>= 1) {
                mn = fminf(mn, __shfl_down(mn, off));
                mx = fmaxf(mx, __shfl_down(mx, off));
            }
            if (lane == 0) { sred[w] = mn; sred[8 + w] = mx; }
            __syncthreads();
            mn = fminf(fminf(fminf(sred[0], sred[1]), fminf(sred[2], sred[3])),
                       fminf(fminf(sred[4], sred[5]), fminf(sred[6], sred[7])));
            mx = fmaxf(fmaxf(fmaxf(sred[8], sred[9]), fmaxf(sred[10], sred[11])),
                       fmaxf(fmaxf(sred[12], sred[13]), fmaxf(sred[14], sred[15])));
            __syncthreads();
            qmn[s] = mn; qsc[s] = (mx - mn) / 255.0f;
        }
    }

    // ---- deep weights -> quantized f16 A-fragments in registers (16-col slice/wave) ----
    half8 bw[NDEEP][4];                  // [layer][kc] : 80 VGPR
#pragma unroll
    for (int i = 0; i < NDEEP; i++) {
        const float mn = qmn[3 + i], sc = qsc[3 + i];
#pragma unroll
        for (int kc = 0; kc < 4; kc++) {
            const float* src = Wd + (size_t)i * HDIM * HDIM
                             + (size_t)(w * 16 + l15) * HDIM + kc * 32 + l4 * 8;
            half8 h;
#pragma unroll
            for (int j = 0; j < 8; j++) h[j] = (_Float16)fquant(src[j], mn, sc);
            bw[i][kc] = h;
        }
    }

    const float a0 = a0p[0];
    float adv[NDEEP];
#pragma unroll
    for (int i = 0; i < NDEEP; i++) adv[i] = adp[i];

    // h0 elementwise: thread owns batch hr (0..15), 4 neurons hc0..hc0+3
    const int hr  = tid >> 5;
    const int hc0 = (tid & 31) * 4;
    float w0v[4], h0v[4];
#pragma unroll
    for (int j = 0; j < 4; j++) {
        w0v[j] = fquant(W0[hc0 + j], qmn[1], qsc[1]);
        h0v[j] = cell_out[(size_t)(r0 + hr) * HDIM + hc0 + j];
    }

    // deep state, D layout: col(batch)=l15, row(neuron)=w*16 + l4*4+j
    f32x4 st[NDEEP];
#pragma unroll
    for (int i = 0; i < NDEEP; i++)
        st[i] = *(const f32x4*)(cell_out + (size_t)(1 + i) * B_TOT * HDIM
                             + (size_t)(r0 + l15) * HDIM + w * 16 + l4 * 4);

    // ---------------- phase 0: pix = quant(x) @ qweight(p1_W)^T + p1_b ----------------
    {
        _Float16* pq = (_Float16*)actp;            // [64][224]  (q rows, zero-padded)
        _Float16* xq = (_Float16*)(actp + 28672);  // [16][224]  (batch rows, zero-padded)
        for (int idx = tid; idx < 16 * 224; idx += 512) {
            int r = idx / 224, p = idx - r * 224;
            float v = 0.0f;
            if (p < PDIM) {
                v = x[(size_t)(r0 + r) * PDIM + p];
                v = fminf(fmaxf(v, -0.45f), 3.55f);
                const float sc = 4.0f / 255.0f;
                v = rintf((v + 0.45f) / sc) * sc - 0.45f;
            }
            xq[idx] = (_Float16)v;
        }
        {
            const float mn = qmn[0], sc = qsc[0];
            for (int idx = tid; idx < 64 * 224; idx += 512) {
                int q = idx / 224, p = idx - q * 224;
                float v = 0.0f;
                if (q < QDIM && p < PDIM) v = fquant(p1W[q * PDIM + p], mn, sc);
                pq[idx] = (_Float16)v;
            }
        }
        __syncthreads();
        if (w < 4) {                               // 4 q-tiles of 16; waves 4-7 idle here
            const int qt = w;
            f32x4 accp = {0.f, 0.f, 0.f, 0.f};
#pragma unroll
            for (int kc = 0; kc < 7; kc++) {
                half8 aF = *(const half8*)(pq + (qt * 16 + l15) * 224 + kc * 32 + l4 * 8);
                half8 bF = *(const half8*)(xq + l15 * 224 + kc * 32 + l4 * 8);
                accp = __builtin_amdgcn_mfma_f32_16x16x32_f16(aF, bF, accp, 0, 0, 0);
            }
#pragma unroll
            for (int j = 0; j < 4; j++) {
                int qj = qt * 16 + l4 * 4 + j;
                accp[j] += (qj < QDIM) ? p1b[qj] : 0.0f;
            }
            *(f32x4*)(pix + l15 * 64 + qt * 16 + l4 * 4) = accp;   // pix[batch][q]
        }
        __syncthreads();
    }

    // ---------------- diagonal-pipelined scan: 54 phases, ONE barrier each ----------------
    const int aswz = (l15 & 7) << 4;
    int boff[4];
#pragma unroll
    for (int kc = 0; kc < 4; kc++)
        boff[kc] = l15 * 256 + ((kc * 64 + l4 * 16) ^ aswz);
    const int woff  = l15 * 256 + ((w * 32 + l4 * 8) ^ aswz);    // C-write (half4)
    const int h0off = hr * 256 + ((hc0 * 2) ^ ((hr & 7) << 4));  // h0 write (half4)
    const float* pixr = pix + hr * 64;

#define PHASE(P, SW, SR)                                                              \
    do {                                                                              \
        if ((P) < QDIM) {                                                             \
            float px = pixr[(P)];                                                     \
            half4 hh;                                                                 \
            _Pragma("unroll") for (int j = 0; j < 4; j++) {                           \
                float v = tanh_fast(fmaf(px, w0v[j], a0 * h0v[j]));                   \
                h0v[j] = v; hh[j] = (_Float16)v;                                      \
            }                                                                         \
            *(half4*)(actp + (SW) * 4096 + h0off) = hh;                               \
        }                                                                             \
        _Pragma("unroll") for (int i = 0; i < NDEEP; i++) {                           \
            int t_ = (P) - 1 - i;                                                     \
            if (t_ >= 0 && t_ < QDIM) {                                               \
                f32x4 acc = st[i] * adv[i];                                           \
                const char* rbase = actp + i * 8192 + (SR) * 4096;                    \
                _Pragma("unroll") for (int kc = 0; kc < 4; kc++) {                    \
                    half8 b_ = *(const half8*)(rbase + boff[kc]);                     \
                    acc = __builtin_amdgcn_mfma_f32_16x16x32_f16(bw[i][kc], b_, acc, 0, 0, 0); \
                }                                                                     \
                half4 hA;                                                             \
                _Pragma("unroll") for (int j = 0; j < 4; j++) {                       \
                    acc[j] = tanh_fast(acc[j]);                                       \
                    hA[j] = (_Float16)acc[j];                                         \
                }                                                                     \
                st[i] = acc;                                                          \
                if (i < NDEEP - 1)                                                    \
                    *(half4*)(actp + (i + 1) * 8192 + (SW) * 4096 + woff) = hA;       \
            }                                                                         \
        }                                                                             \
        __syncthreads();                                                              \
    } while (0)

#pragma unroll 1
    for (int p = 0; p < NPHASE; p += 2) {
        PHASE(p,     0, 1);
        PHASE(p + 1, 1, 0);
    }
#undef PHASE

    // ---------------- epilogue: out = relu(hs4 @ qweight(fc1)^T) @ fc2^T + fc2b ----------------
    float* hs4 = (float*)actp;                       // [16][136] (16B-aligned row stride)
    *(f32x4*)(hs4 + l15 * 136 + w * 16 + l4 * 4) = st[NDEEP - 1];
    __syncthreads();

    float* tmp = pix;                                // [16][8]
    if (tid < 128) {
        int r = tid >> 3, jj = tid & 7;
        const float* hrow = hs4 + r * 136;
        const float* fw   = fc1W + jj * HDIM;
        const float mn = qmn[2], sc = qsc[2];
        float acc = 0.f;
#pragma unroll 4
        for (int p = 0; p < HDIM; p++) acc += hrow[p] * fquant(fw[p], mn, sc);
        tmp[r * 8 + jj] = fmaxf(acc, 0.f);
    }
    __syncthreads();
    if (tid < 160) {
        int r = tid / 10, o = tid - r * 10;
        float acc = fc2b[o];
#pragma unroll
        for (int jj = 0; jj < 8; jj++) acc += tmp[r * 8 + jj] * fc2W[o * 8 + jj];
        out[(size_t)(r0 + r) * 10 + o] = acc;
    }
}

extern "C" void kernel_launch(void* const* d_in, const int* in_sizes, int n_in,
                              void* d_out, int out_size, void* d_ws, size_t ws_size,
                              hipStream_t stream)
{
    const float* x    = (const float*)d_in[0];
    const float* cell = (const float*)d_in[1];
    const float* W0   = (const float*)d_in[2];
    const float* a0   = (const float*)d_in[3];
    const float* Wd   = (const float*)d_in[4];
    const float* ad   = (const float*)d_in[5];
    const float* p1W  = (const float*)d_in[6];
    const float* p1b  = (const float*)d_in[7];
    const float* fc1  = (const float*)d_in[8];
    const float* fc2W = (const float*)d_in[9];
    const float* fc2b = (const float*)d_in[10];

    dfr_all<<<512, 512, 0, stream>>>(x, cell, W0, a0, Wd, ad, p1W, p1b,
                                     fc1, fc2W, fc2b, (float*)d_out);
}

// Round 7
// 392.186 us; speedup vs baseline: 2.9904x; 2.9904x over previous
//
#include <hip/hip_runtime.h>
#include <hip/hip_fp16.h>

typedef __attribute__((ext_vector_type(8))) _Float16 half8;
typedef __attribute__((ext_vector_type(4))) _Float16 half4;
typedef __attribute__((ext_vector_type(4))) float f32x4;

#define B_TOT 8192
#define HDIM  128
#define NDEEP 5
#define PDIM  196
#define QDIM  49
#define BM    16
#define NPHASE (QDIM + NDEEP)   // 54, even

__device__ __forceinline__ float tanh_fast(float v) {
    // tanh(v) = 1 - 2/(exp(2v)+1); exp(2v) = exp2(v * 2*log2(e)). Saturates at +-inf.
    float e = __builtin_amdgcn_exp2f(v * 2.885390082f);
    float r = __builtin_amdgcn_rcpf(e + 1.0f);
    return fmaf(-2.0f, r, 1.0f);
}

__device__ __forceinline__ float fquant(float v, float mn, float sc) {
    // 8-bit uniform fake-quant: IEEE f32 div + rint (half-even) to match numpy
    return rintf((v - mn) / sc) * sc + mn;
}

// Fully fused DFR. grid=512 x 512 thr (8 waves); LDS 44 KB + VGPR<=128 -> 2 blocks/CU
// (16 waves/CU) with INDEPENDENT barriers for cross-block overlap.
// NOTE: no min-waves arg in __launch_bounds__ — empirically (512,4) made hipcc emit a
// 64-reg allocation and spill the 80-VGPR weight fragments in-loop (round 6: 4.3 GB
// scratch traffic). Plain (512) yields 128 regs (round 5 evidence).
// Block owns 16 batch rows; wave w owns out-neuron cols [w*16, w*16+16).
// Diagonal pipeline: phase p runs h0(t=p) and deep layer i at t=p-1-i; one barrier
// per phase (54 total). fc1's min/max is recomputed in the epilogue to keep the
// scan-loop register set minimal.
__global__ __launch_bounds__(512) void dfr_all(
    const float* __restrict__ x,    const float* __restrict__ cell_out,
    const float* __restrict__ W0,   const float* __restrict__ a0p,
    const float* __restrict__ Wd,   const float* __restrict__ adp,
    const float* __restrict__ p1W,  const float* __restrict__ p1b,
    const float* __restrict__ fc1W, const float* __restrict__ fc2W,
    const float* __restrict__ fc2b, float* __restrict__ out)
{
    __shared__ __align__(16) char smem[4096 + 10 * 4096];   // 44 KB
    float* pix  = (float*)smem;          // [16 batch][64] f32 (q cols 0..48 valid)
    char*  actp = smem + 4096;           // act[producer 0..4][slot 0..1]: 16 rows x 256 B, swizzled

    const int tid  = threadIdx.x;
    const int lane = tid & 63;
    const int w    = tid >> 6;           // wave 0..7 (owns out-neuron cols w*16..w*16+15)
    const int l15  = lane & 15;
    const int l4   = lane >> 4;
    const int r0   = blockIdx.x * BM;

    float* sred = (float*)smem;          // 16-float reduce scratch (dead before pix written)

    // helper: block-wide min/max of tensor p[0..n)  (all 512 threads)
#define MINMAX(p_, n_, MN, SC)                                                        \
    do {                                                                              \
        float mn_ = 1e30f, mx_ = -1e30f;                                              \
        for (int i_ = tid; i_ < (n_); i_ += 512) {                                    \
            float v_ = (p_)[i_]; mn_ = fminf(mn_, v_); mx_ = fmaxf(mx_, v_);          \
        }                                                                             \
        for (int o_ = 32; o_; o_ >>= 1) {                                             \
            mn_ = fminf(mn_, __shfl_down(mn_, o_));                                   \
            mx_ = fmaxf(mx_, __shfl_down(mx_, o_));                                   \
        }                                                                             \
        if (lane == 0) { sred[w] = mn_; sred[8 + w] = mx_; }                          \
        __syncthreads();                                                              \
        mn_ = fminf(fminf(fminf(sred[0], sred[1]), fminf(sred[2], sred[3])),          \
                    fminf(fminf(sred[4], sred[5]), fminf(sred[6], sred[7])));         \
        mx_ = fmaxf(fmaxf(fmaxf(sred[8], sred[9]), fmaxf(sred[10], sred[11])),        \
                    fmaxf(fmaxf(sred[12], sred[13]), fmaxf(sred[14], sred[15])));     \
        __syncthreads();                                                              \
        (MN) = mn_; (SC) = (mx_ - mn_) / 255.0f;                                      \
    } while (0)

    // ---- W0 -> w0v (consumed immediately) ----
    const int hr  = tid >> 5;            // 0..15
    const int hc0 = (tid & 31) * 4;
    float w0v[4], h0v[4];
    {
        float mn, sc;
        MINMAX(W0, HDIM, mn, sc);
#pragma unroll
        for (int j = 0; j < 4; j++) {
            w0v[j] = fquant(W0[hc0 + j], mn, sc);
            h0v[j] = cell_out[(size_t)(r0 + hr) * HDIM + hc0 + j];
        }
    }

    // ---- deep weights -> quantized f16 A-fragments in registers (consumed per-tensor) ----
    half8 bw[NDEEP][4];                  // [layer][kc] : 80 VGPR
#pragma unroll
    for (int i = 0; i < NDEEP; i++) {
        float mn, sc;
        MINMAX(Wd + (size_t)i * HDIM * HDIM, HDIM * HDIM, mn, sc);
#pragma unroll
        for (int kc = 0; kc < 4; kc++) {
            const float* src = Wd + (size_t)i * HDIM * HDIM
                             + (size_t)(w * 16 + l15) * HDIM + kc * 32 + l4 * 8;
            half8 h;
#pragma unroll
            for (int j = 0; j < 8; j++) h[j] = (_Float16)fquant(src[j], mn, sc);
            bw[i][kc] = h;
        }
    }

    const float a0 = a0p[0];
    float adv[NDEEP];
#pragma unroll
    for (int i = 0; i < NDEEP; i++) adv[i] = adp[i];

    // deep state, D layout: col(batch)=l15, row(neuron)=w*16 + l4*4+j
    f32x4 st[NDEEP];
#pragma unroll
    for (int i = 0; i < NDEEP; i++)
        st[i] = *(const f32x4*)(cell_out + (size_t)(1 + i) * B_TOT * HDIM
                             + (size_t)(r0 + l15) * HDIM + w * 16 + l4 * 4);

    // ---------------- phase 0: pix = quant(x) @ qweight(p1_W)^T + p1_b ----------------
    {
        float p1mn, p1sc;
        MINMAX(p1W, QDIM * PDIM, p1mn, p1sc);
        _Float16* pq = (_Float16*)actp;            // [64][224]  (q rows, zero-padded)
        _Float16* xq = (_Float16*)(actp + 28672);  // [16][224]  (batch rows, zero-padded)
        for (int idx = tid; idx < 16 * 224; idx += 512) {
            int r = idx / 224, p = idx - r * 224;
            float v = 0.0f;
            if (p < PDIM) {
                v = x[(size_t)(r0 + r) * PDIM + p];
                v = fminf(fmaxf(v, -0.45f), 3.55f);
                const float sc = 4.0f / 255.0f;
                v = rintf((v + 0.45f) / sc) * sc - 0.45f;
            }
            xq[idx] = (_Float16)v;
        }
        for (int idx = tid; idx < 64 * 224; idx += 512) {
            int q = idx / 224, p = idx - q * 224;
            float v = 0.0f;
            if (q < QDIM && p < PDIM) v = fquant(p1W[q * PDIM + p], p1mn, p1sc);
            pq[idx] = (_Float16)v;
        }
        __syncthreads();
        if (w < 4) {                               // 4 q-tiles of 16; waves 4-7 idle here
            const int qt = w;
            f32x4 accp = {0.f, 0.f, 0.f, 0.f};
#pragma unroll
            for (int kc = 0; kc < 7; kc++) {
                half8 aF = *(const half8*)(pq + (qt * 16 + l15) * 224 + kc * 32 + l4 * 8);
                half8 bF = *(const half8*)(xq + l15 * 224 + kc * 32 + l4 * 8);
                accp = __builtin_amdgcn_mfma_f32_16x16x32_f16(aF, bF, accp, 0, 0, 0);
            }
#pragma unroll
            for (int j = 0; j < 4; j++) {
                int qj = qt * 16 + l4 * 4 + j;
                accp[j] += (qj < QDIM) ? p1b[qj] : 0.0f;
            }
            *(f32x4*)(pix + l15 * 64 + qt * 16 + l4 * 4) = accp;   // pix[batch][q]
        }
        __syncthreads();
    }

    // ---------------- diagonal-pipelined scan: 54 phases, ONE barrier each ----------------
    const int aswz  = (l15 & 7) << 4;                            // read-side XOR swizzle
    const int rrow  = l15 * 256;                                 // B-frag row base
    const int woff  = l15 * 256 + ((w * 32 + l4 * 8) ^ aswz);    // C-write (half4)
    const int h0off = hr * 256 + ((hc0 * 2) ^ ((hr & 7) << 4));  // h0 write (half4)
    const float* pixr = pix + hr * 64;

#define PHASE(P, SW, SR)                                                              \
    do {                                                                              \
        if ((P) < QDIM) {                                                             \
            float px = pixr[(P)];                                                     \
            half4 hh;                                                                 \
            _Pragma("unroll") for (int j = 0; j < 4; j++) {                           \
                float v = tanh_fast(fmaf(px, w0v[j], a0 * h0v[j]));                   \
                h0v[j] = v; hh[j] = (_Float16)v;                                      \
            }                                                                         \
            *(half4*)(actp + (SW) * 4096 + h0off) = hh;                               \
        }                                                                             \
        _Pragma("unroll") for (int i = 0; i < NDEEP; i++) {                           \
            int t_ = (P) - 1 - i;                                                     \
            if (t_ >= 0 && t_ < QDIM) {                                               \
                f32x4 acc = st[i] * adv[i];                                           \
                const char* rbase = actp + i * 8192 + (SR) * 4096 + rrow;             \
                _Pragma("unroll") for (int kc = 0; kc < 4; kc++) {                    \
                    half8 b_ = *(const half8*)(rbase + (((kc * 64) + (l4 * 16)) ^ aswz)); \
                    acc = __builtin_amdgcn_mfma_f32_16x16x32_f16(bw[i][kc], b_, acc, 0, 0, 0); \
                }                                                                     \
                half4 hA;                                                             \
                _Pragma("unroll") for (int j = 0; j < 4; j++) {                       \
                    acc[j] = tanh_fast(acc[j]);                                       \
                    hA[j] = (_Float16)acc[j];                                         \
                }                                                                     \
                st[i] = acc;                                                          \
                if (i < NDEEP - 1)                                                    \
                    *(half4*)(actp + (i + 1) * 8192 + (SW) * 4096 + woff) = hA;       \
            }                                                                         \
        }                                                                             \
        __syncthreads();                                                              \
    } while (0)

#pragma unroll 1
    for (int p = 0; p < NPHASE; p += 2) {
        PHASE(p,     0, 1);
        PHASE(p + 1, 1, 0);
    }
#undef PHASE

    // ---------------- epilogue: out = relu(hs4 @ qweight(fc1)^T) @ fc2^T + fc2b ----------------
    float* hs4 = (float*)actp;                       // [16][136] (16B-aligned row stride)
    *(f32x4*)(hs4 + l15 * 136 + w * 16 + l4 * 4) = st[NDEEP - 1];

    float fmn, fsc;                                  // fc1 min/max recomputed here (reg relief)
    {
        float mn_ = 1e30f, mx_ = -1e30f;
        for (int i_ = tid; i_ < 8 * HDIM; i_ += 512) {
            float v_ = fc1W[i_]; mn_ = fminf(mn_, v_); mx_ = fmaxf(mx_, v_);
        }
        for (int o_ = 32; o_; o_ >>= 1) {
            mn_ = fminf(mn_, __shfl_down(mn_, o_));
            mx_ = fmaxf(mx_, __shfl_down(mx_, o_));
        }
        float* sred2 = (float*)(smem + 2048);        // clear of tmp region below
        if (lane == 0) { sred2[w] = mn_; sred2[8 + w] = mx_; }
        __syncthreads();                             // also makes hs4 stores visible
        fmn = fminf(fminf(fminf(sred2[0], sred2[1]), fminf(sred2[2], sred2[3])),
                    fminf(fminf(sred2[4], sred2[5]), fminf(sred2[6], sred2[7])));
        float fmx = fmaxf(fmaxf(fmaxf(sred2[8], sred2[9]), fmaxf(sred2[10], sred2[11])),
                          fmaxf(fmaxf(sred2[12], sred2[13]), fmaxf(sred2[14], sred2[15])));
        fsc = (fmx - fmn) / 255.0f;
    }

    float* tmp = pix;                                // [16][8] at smem+0 (sred2 at +2048)
    if (tid < 128) {
        int r = tid >> 3, jj = tid & 7;
        const float* hrow = hs4 + r * 136;
        const float* fw   = fc1W + jj * HDIM;
        float acc = 0.f;
#pragma unroll 4
        for (int p = 0; p < HDIM; p++) acc += hrow[p] * fquant(fw[p], fmn, fsc);
        tmp[r * 8 + jj] = fmaxf(acc, 0.f);
    }
    __syncthreads();
    if (tid < 160) {
        int r = tid / 10, o = tid - r * 10;
        float acc = fc2b[o];
#pragma unroll
        for (int jj = 0; jj < 8; jj++) acc += tmp[r * 8 + jj] * fc2W[o * 8 + jj];
        out[(size_t)(r0 + r) * 10 + o] = acc;
    }
#undef MINMAX
}

extern "C" void kernel_launch(void* const* d_in, const int* in_sizes, int n_in,
                              void* d_out, int out_size, void* d_ws, size_t ws_size,
                              hipStream_t stream)
{
    const float* x    = (const float*)d_in[0];
    const float* cell = (const float*)d_in[1];
    const float* W0   = (const float*)d_in[2];
    const float* a0   = (const float*)d_in[3];
    const float* Wd   = (const float*)d_in[4];
    const float* ad   = (const float*)d_in[5];
    const float* p1W  = (const float*)d_in[6];
    const float* p1b  = (const float*)d_in[7];
    const float* fc1  = (const float*)d_in[8];
    const float* fc2W = (const float*)d_in[9];
    const float* fc2b = (const float*)d_in[10];

    dfr_all<<<512, 512, 0, stream>>>(x, cell, W0, a0, Wd, ad, p1W, p1b,
                                     fc1, fc2W, fc2b, (float*)d_out);
}

// Round 8
// 391.734 us; speedup vs baseline: 2.9939x; 1.0012x over previous
//
#include <hip/hip_runtime.h>
#include <hip/hip_fp16.h>

typedef __attribute__((ext_vector_type(8))) _Float16 half8;
typedef __attribute__((ext_vector_type(4))) _Float16 half4;
typedef __attribute__((ext_vector_type(4))) float f32x4;

#define B_TOT 8192
#define HDIM  128
#define NDEEP 5
#define PDIM  196
#define QDIM  49
#define BM    16
#define NPHASE (QDIM + NDEEP)   // 54, even

__device__ __forceinline__ float tanh_fast(float v) {
    // tanh(v) = 1 - 2/(exp(2v)+1); exp(2v) = exp2(v * 2*log2(e)). Saturates at +-inf.
    float e = __builtin_amdgcn_exp2f(v * 2.885390082f);
    float r = __builtin_amdgcn_rcpf(e + 1.0f);
    return fmaf(-2.0f, r, 1.0f);
}

__device__ __forceinline__ float fquant(float v, float mn, float sc) {
    // 8-bit uniform fake-quant: IEEE f32 div + rint (half-even) to match numpy
    return rintf((v - mn) / sc) * sc + mn;
}

// Fully fused DFR. grid=512 x 512 thr (8 waves).
// __launch_bounds__(512, 2): 2nd arg is min BLOCKS per CU (standard HIP semantics —
// verified empirically: (256,2)->216 regs, (512,4)->64 regs; both match blocks-per-CU,
// not the waves-per-EU formula). => reg cap 128 INCLUDING AGPRs, so two 44 KB blocks
// co-reside per CU: 16 waves/CU with independent barriers for cross-block overlap.
// Round 7 (no bound) compiled to 124 arch VGPRs but did NOT co-reside (occupancy 23.6%),
// implying unified-file AGPR overhead pushed effective allocation past 128.
// Block owns 16 batch rows; wave w owns out-neuron cols [w*16, w*16+16).
// Diagonal pipeline: phase p runs h0(t=p) and deep layer i at t=p-1-i; one barrier
// per phase (54 total). fc1's min/max recomputed in the epilogue for reg relief.
__global__ __launch_bounds__(512, 2) void dfr_all(
    const float* __restrict__ x,    const float* __restrict__ cell_out,
    const float* __restrict__ W0,   const float* __restrict__ a0p,
    const float* __restrict__ Wd,   const float* __restrict__ adp,
    const float* __restrict__ p1W,  const float* __restrict__ p1b,
    const float* __restrict__ fc1W, const float* __restrict__ fc2W,
    const float* __restrict__ fc2b, float* __restrict__ out)
{
    __shared__ __align__(16) char smem[4096 + 10 * 4096];   // 44 KB
    float* pix  = (float*)smem;          // [16 batch][64] f32 (q cols 0..48 valid)
    char*  actp = smem + 4096;           // act[producer 0..4][slot 0..1]: 16 rows x 256 B, swizzled

    const int tid  = threadIdx.x;
    const int lane = tid & 63;
    const int w    = tid >> 6;           // wave 0..7 (owns out-neuron cols w*16..w*16+15)
    const int l15  = lane & 15;
    const int l4   = lane >> 4;
    const int r0   = blockIdx.x * BM;

    float* sred = (float*)smem;          // 16-float reduce scratch (dead before pix written)

    // helper: block-wide min/max of tensor p[0..n)  (all 512 threads)
#define MINMAX(p_, n_, MN, SC)                                                        \
    do {                                                                              \
        float mn_ = 1e30f, mx_ = -1e30f;                                              \
        for (int i_ = tid; i_ < (n_); i_ += 512) {                                    \
            float v_ = (p_)[i_]; mn_ = fminf(mn_, v_); mx_ = fmaxf(mx_, v_);          \
        }                                                                             \
        for (int o_ = 32; o_; o_ >>= 1) {                                             \
            mn_ = fminf(mn_, __shfl_down(mn_, o_));                                   \
            mx_ = fmaxf(mx_, __shfl_down(mx_, o_));                                   \
        }                                                                             \
        if (lane == 0) { sred[w] = mn_; sred[8 + w] = mx_; }                          \
        __syncthreads();                                                              \
        mn_ = fminf(fminf(fminf(sred[0], sred[1]), fminf(sred[2], sred[3])),          \
                    fminf(fminf(sred[4], sred[5]), fminf(sred[6], sred[7])));         \
        mx_ = fmaxf(fmaxf(fmaxf(sred[8], sred[9]), fmaxf(sred[10], sred[11])),        \
                    fmaxf(fmaxf(sred[12], sred[13]), fmaxf(sred[14], sred[15])));     \
        __syncthreads();                                                              \
        (MN) = mn_; (SC) = (mx_ - mn_) / 255.0f;                                      \
    } while (0)

    // ---- W0 -> w0v (consumed immediately) ----
    const int hr  = tid >> 5;            // 0..15
    const int hc0 = (tid & 31) * 4;
    float w0v[4], h0v[4];
    {
        float mn, sc;
        MINMAX(W0, HDIM, mn, sc);
#pragma unroll
        for (int j = 0; j < 4; j++) {
            w0v[j] = fquant(W0[hc0 + j], mn, sc);
            h0v[j] = cell_out[(size_t)(r0 + hr) * HDIM + hc0 + j];
        }
    }

    // ---- deep weights -> quantized f16 A-fragments in registers (consumed per-tensor) ----
    half8 bw[NDEEP][4];                  // [layer][kc] : 80 VGPR
#pragma unroll
    for (int i = 0; i < NDEEP; i++) {
        float mn, sc;
        MINMAX(Wd + (size_t)i * HDIM * HDIM, HDIM * HDIM, mn, sc);
#pragma unroll
        for (int kc = 0; kc < 4; kc++) {
            const float* src = Wd + (size_t)i * HDIM * HDIM
                             + (size_t)(w * 16 + l15) * HDIM + kc * 32 + l4 * 8;
            half8 h;
#pragma unroll
            for (int j = 0; j < 8; j++) h[j] = (_Float16)fquant(src[j], mn, sc);
            bw[i][kc] = h;
        }
    }

    const float a0 = a0p[0];
    float adv[NDEEP];
#pragma unroll
    for (int i = 0; i < NDEEP; i++) adv[i] = adp[i];

    // deep state, D layout: col(batch)=l15, row(neuron)=w*16 + l4*4+j
    f32x4 st[NDEEP];
#pragma unroll
    for (int i = 0; i < NDEEP; i++)
        st[i] = *(const f32x4*)(cell_out + (size_t)(1 + i) * B_TOT * HDIM
                             + (size_t)(r0 + l15) * HDIM + w * 16 + l4 * 4);

    // ---------------- phase 0: pix = quant(x) @ qweight(p1_W)^T + p1_b ----------------
    {
        float p1mn, p1sc;
        MINMAX(p1W, QDIM * PDIM, p1mn, p1sc);
        _Float16* pq = (_Float16*)actp;            // [64][224]  (q rows, zero-padded)
        _Float16* xq = (_Float16*)(actp + 28672);  // [16][224]  (batch rows, zero-padded)
        for (int idx = tid; idx < 16 * 224; idx += 512) {
            int r = idx / 224, p = idx - r * 224;
            float v = 0.0f;
            if (p < PDIM) {
                v = x[(size_t)(r0 + r) * PDIM + p];
                v = fminf(fmaxf(v, -0.45f), 3.55f);
                const float sc = 4.0f / 255.0f;
                v = rintf((v + 0.45f) / sc) * sc - 0.45f;
            }
            xq[idx] = (_Float16)v;
        }
        for (int idx = tid; idx < 64 * 224; idx += 512) {
            int q = idx / 224, p = idx - q * 224;
            float v = 0.0f;
            if (q < QDIM && p < PDIM) v = fquant(p1W[q * PDIM + p], p1mn, p1sc);
            pq[idx] = (_Float16)v;
        }
        __syncthreads();
        if (w < 4) {                               // 4 q-tiles of 16; waves 4-7 idle here
            const int qt = w;
            f32x4 accp = {0.f, 0.f, 0.f, 0.f};
#pragma unroll
            for (int kc = 0; kc < 7; kc++) {
                half8 aF = *(const half8*)(pq + (qt * 16 + l15) * 224 + kc * 32 + l4 * 8);
                half8 bF = *(const half8*)(xq + l15 * 224 + kc * 32 + l4 * 8);
                accp = __builtin_amdgcn_mfma_f32_16x16x32_f16(aF, bF, accp, 0, 0, 0);
            }
#pragma unroll
            for (int j = 0; j < 4; j++) {
                int qj = qt * 16 + l4 * 4 + j;
                accp[j] += (qj < QDIM) ? p1b[qj] : 0.0f;
            }
            *(f32x4*)(pix + l15 * 64 + qt * 16 + l4 * 4) = accp;   // pix[batch][q]
        }
        __syncthreads();
    }

    // ---------------- diagonal-pipelined scan: 54 phases, ONE barrier each ----------------
    const int aswz  = (l15 & 7) << 4;                            // read-side XOR swizzle
    const int rrow  = l15 * 256;                                 // B-frag row base
    const int woff  = l15 * 256 + ((w * 32 + l4 * 8) ^ aswz);    // C-write (half4)
    const int h0off = hr * 256 + ((hc0 * 2) ^ ((hr & 7) << 4));  // h0 write (half4)
    const float* pixr = pix + hr * 64;

#define PHASE(P, SW, SR)                                                              \
    do {                                                                              \
        if ((P) < QDIM) {                                                             \
            float px = pixr[(P)];                                                     \
            half4 hh;                                                                 \
            _Pragma("unroll") for (int j = 0; j < 4; j++) {                           \
                float v = tanh_fast(fmaf(px, w0v[j], a0 * h0v[j]));                   \
                h0v[j] = v; hh[j] = (_Float16)v;                                      \
            }                                                                         \
            *(half4*)(actp + (SW) * 4096 + h0off) = hh;                               \
        }                                                                             \
        _Pragma("unroll") for (int i = 0; i < NDEEP; i++) {                           \
            int t_ = (P) - 1 - i;                                                     \
            if (t_ >= 0 && t_ < QDIM) {                                               \
                f32x4 acc = st[i] * adv[i];                                           \
                const char* rbase = actp + i * 8192 + (SR) * 4096 + rrow;             \
                _Pragma("unroll") for (int kc = 0; kc < 4; kc++) {                    \
                    half8 b_ = *(const half8*)(rbase + (((kc * 64) + (l4 * 16)) ^ aswz)); \
                    acc = __builtin_amdgcn_mfma_f32_16x16x32_f16(bw[i][kc], b_, acc, 0, 0, 0); \
                }                                                                     \
                half4 hA;                                                             \
                _Pragma("unroll") for (int j = 0; j < 4; j++) {                       \
                    acc[j] = tanh_fast(acc[j]);                                       \
                    hA[j] = (_Float16)acc[j];                                         \
                }                                                                     \
                st[i] = acc;                                                          \
                if (i < NDEEP - 1)                                                    \
                    *(half4*)(actp + (i + 1) * 8192 + (SW) * 4096 + woff) = hA;       \
            }                                                                         \
        }                                                                             \
        __syncthreads();                                                              \
    } while (0)

#pragma unroll 1
    for (int p = 0; p < NPHASE; p += 2) {
        PHASE(p,     0, 1);
        PHASE(p + 1, 1, 0);
    }
#undef PHASE

    // ---------------- epilogue: out = relu(hs4 @ qweight(fc1)^T) @ fc2^T + fc2b ----------------
    float* hs4 = (float*)actp;                       // [16][136] (16B-aligned row stride)
    *(f32x4*)(hs4 + l15 * 136 + w * 16 + l4 * 4) = st[NDEEP - 1];

    float fmn, fsc;                                  // fc1 min/max recomputed here (reg relief)
    {
        float mn_ = 1e30f, mx_ = -1e30f;
        for (int i_ = tid; i_ < 8 * HDIM; i_ += 512) {
            float v_ = fc1W[i_]; mn_ = fminf(mn_, v_); mx_ = fmaxf(mx_, v_);
        }
        for (int o_ = 32; o_; o_ >>= 1) {
            mn_ = fminf(mn_, __shfl_down(mn_, o_));
            mx_ = fmaxf(mx_, __shfl_down(mx_, o_));
        }
        float* sred2 = (float*)(smem + 2048);        // clear of tmp region below
        if (lane == 0) { sred2[w] = mn_; sred2[8 + w] = mx_; }
        __syncthreads();                             // also makes hs4 stores visible
        fmn = fminf(fminf(fminf(sred2[0], sred2[1]), fminf(sred2[2], sred2[3])),
                    fminf(fminf(sred2[4], sred2[5]), fminf(sred2[6], sred2[7])));
        float fmx = fmaxf(fmaxf(fmaxf(sred2[8], sred2[9]), fmaxf(sred2[10], sred2[11])),
                          fmaxf(fmaxf(sred2[12], sred2[13]), fmaxf(sred2[14], sred2[15])));
        fsc = (fmx - fmn) / 255.0f;
    }

    float* tmp = pix;                                // [16][8] at smem+0 (sred2 at +2048)
    if (tid < 128) {
        int r = tid >> 3, jj = tid & 7;
        const float* hrow = hs4 + r * 136;
        const float* fw   = fc1W + jj * HDIM;
        float acc = 0.f;
#pragma unroll 4
        for (int p = 0; p < HDIM; p++) acc += hrow[p] * fquant(fw[p], fmn, fsc);
        tmp[r * 8 + jj] = fmaxf(acc, 0.f);
    }
    __syncthreads();
    if (tid < 160) {
        int r = tid / 10, o = tid - r * 10;
        float acc = fc2b[o];
#pragma unroll
        for (int jj = 0; jj < 8; jj++) acc += tmp[r * 8 + jj] * fc2W[o * 8 + jj];
        out[(size_t)(r0 + r) * 10 + o] = acc;
    }
#undef MINMAX
}

extern "C" void kernel_launch(void* const* d_in, const int* in_sizes, int n_in,
                              void* d_out, int out_size, void* d_ws, size_t ws_size,
                              hipStream_t stream)
{
    const float* x    = (const float*)d_in[0];
    const float* cell = (const float*)d_in[1];
    const float* W0   = (const float*)d_in[2];
    const float* a0   = (const float*)d_in[3];
    const float* Wd   = (const float*)d_in[4];
    const float* ad   = (const float*)d_in[5];
    const float* p1W  = (const float*)d_in[6];
    const float* p1b  = (const float*)d_in[7];
    const float* fc1  = (const float*)d_in[8];
    const float* fc2W = (const float*)d_in[9];
    const float* fc2b = (const float*)d_in[10];

    dfr_all<<<512, 512, 0, stream>>>(x, cell, W0, a0, Wd, ad, p1W, p1b,
                                     fc1, fc2W, fc2b, (float*)d_out);
}